// Round 13
// baseline (232.674 us; speedup 1.0000x reference)
//
#include <hip/hip_runtime.h>

#define BB 2
#define NN 8192
#define KK 16
#define QPB 64
#define STASH 32         // per-thread survivor id stash (LDS); overflow -> inline insert
#define EPSF 0.02f       // bf16-hi/lo MFMA distance error slack (bound ~3e-3, >3x margin)
typedef unsigned long long ull;
typedef unsigned short ushort;
#define KINF 0xFFFFFFFFFFFFFFFFULL
#define BFONE 0x3F80

typedef __attribute__((ext_vector_type(8))) short short8;
typedef __attribute__((ext_vector_type(4))) float f32x4;

#if __has_builtin(__builtin_amdgcn_fmed3f)
#define MED3(a,b,c) __builtin_amdgcn_fmed3f((a),(b),(c))
#else
#define MED3(a,b,c) fmaxf(fminf((a),(b)), fminf(fmaxf((a),(b)),(c)))
#endif

static __device__ __forceinline__ ushort f2bf(float f) {
    unsigned u = __float_as_uint(f);
    unsigned r = (u + 0x7FFFu + ((u >> 16) & 1u)) >> 16;
    return (ushort)r;
}
static __device__ __forceinline__ float bf2f(ushort s) {
    return __uint_as_float(((unsigned)s) << 16);
}

// exact distance form used by select (consistent => thr conservative):
// d = fma(qx,cnx, fma(qy,cny, fma(qz,cnz, qw+cnw))), cn = (-2x,-2y,-2z,sq)
static __device__ __forceinline__ float distq(const float4& qp, const float4& cn) {
    return fmaf(qp.x, cn.x, fmaf(qp.y, cn.y, fmaf(qp.z, cn.z, __fadd_rn(qp.w, cn.w))));
}

// ---------------------------------------------------------------- prep + f1 + weight pre-conversion
// blocks 0..63: pts4/pts4n/ptsC64 | 64..191: f1 (128 pts/block, 2 thr/pt)
// 192..199: weight bf16 pre-conversion
__global__ __launch_bounds__(256) void prep_f1_kernel(
    const float* __restrict__ x, float4* __restrict__ pts4, float4* __restrict__ pts4n,
    ushort* __restrict__ ptsC64,
    const float* __restrict__ w1, const float* __restrict__ b1,
    const float* __restrict__ w2, const float* __restrict__ b2,
    ushort* __restrict__ f1,
    const float* __restrict__ aw1, const float* __restrict__ aw2,
    const float* __restrict__ m3w1, const float* __restrict__ m3w2,
    ushort* __restrict__ awb1, ushort* __restrict__ awb2,
    ushort* __restrict__ m3w1b, ushort* __restrict__ m3w2b)
{
    if (blockIdx.x >= 192) {
        // ------------------------------ weight bf16 pre-conversion (blocks 192..199)
        int wt = (blockIdx.x - 192) * 256 + threadIdx.x;   // 0..2047
        for (int c = wt; c < 7552; c += 2048) {
            int i = c * 4;
            const float* s; ushort* d; int off;
            if (i < 8192)       { s = aw1;  d = awb1;  off = i; }
            else if (i < 16384) { s = aw2;  d = awb2;  off = i - 8192; }
            else if (i < 28672) { s = m3w1; d = m3w1b; off = i - 16384; }
            else                { s = m3w2; d = m3w2b; off = i - 28672; }
            float4 v = *(const float4*)(s + off);
            ushort4 o = { f2bf(v.x), f2bf(v.y), f2bf(v.z), f2bf(v.w) };
            *(ushort4*)(d + off) = o;
        }
        return;
    }
    if (blockIdx.x < 64) {
        int t = blockIdx.x * 256 + threadIdx.x;
        int b = t >> 13, n = t & (NN - 1);
        float x0 = x[(b * 3 + 0) * NN + n];
        float x1 = x[(b * 3 + 1) * NN + n];
        float x2 = x[(b * 3 + 2) * NN + n];
        float sq = fmaf(x2, x2, fmaf(x1, x1, __fmul_rn(x0, x0)));
        pts4[t]  = make_float4(x0, x1, x2, sq);
        pts4n[t] = make_float4(-2.f * x0, -2.f * x1, -2.f * x2, sq);

        // MFMA candidate row: K=16 bf16 (hi/lo split), padded to 32 (64B)
        float m2x = -2.f * x0, m2y = -2.f * x1, m2z = -2.f * x2;
        ushort hx = f2bf(m2x), hy = f2bf(m2y), hz = f2bf(m2z);
        ushort lx = f2bf(m2x - bf2f(hx));
        ushort ly = f2bf(m2y - bf2f(hy));
        ushort lz = f2bf(m2z - bf2f(hz));
        ushort sh = f2bf(sq), sl = f2bf(sq - bf2f(sh));
        short8 r0 = { (short)hx, (short)hy, (short)hz, (short)lx,
                      (short)ly, (short)lz, (short)hx, (short)hy };
        short8 r1 = { (short)hz, (short)lx, (short)ly, (short)lz,
                      (short)sh, (short)sl, (short)BFONE, (short)BFONE };
        short8 zz = { 0, 0, 0, 0, 0, 0, 0, 0 };
        ushort* cp = ptsC64 + (size_t)t * 32;
        *(short8*)(cp)      = r0;
        *(short8*)(cp + 8)  = r1;
        *(short8*)(cp + 16) = zz;
        *(short8*)(cp + 24) = zz;
    } else {
        // f1: 128 blocks x 128 points, 2 threads/point (t&1 = output half)
        int P = (blockIdx.x - 64) * 128 + (threadIdx.x >> 1);
        int half = threadIdx.x & 1;
        int b = P >> 13, n = P & (NN - 1);
        float x0 = x[(b * 3 + 0) * NN + n];
        float x1 = x[(b * 3 + 1) * NN + n];
        float x2 = x[(b * 3 + 2) * NN + n];
        float h[32];
#pragma unroll
        for (int o = 0; o < 32; ++o) {
            float v = fmaf(w1[o * 3 + 2], x2, fmaf(w1[o * 3 + 1], x1, fmaf(w1[o * 3 + 0], x0, b1[o])));
            h[o] = fmaxf(v, 0.f);
        }
#pragma unroll
        for (int i = 0; i < 8; ++i) {
            int o4 = half * 8 + i;
            float vv[4];
#pragma unroll
            for (int u = 0; u < 4; ++u) {
                int o = o4 * 4 + u;
                float v = b2[o];
#pragma unroll
                for (int k = 0; k < 32; ++k) v = fmaf(w2[o * 32 + k], h[k], v);
                vv[u] = fmaxf(v, 0.f);
            }
            ushort4 s = { f2bf(vv[0]), f2bf(vv[1]), f2bf(vv[2]), f2bf(vv[3]) };
            *(ushort4*)(f1 + (size_t)P * 64 + o4 * 4) = s;
        }
    }
}

// ---------------------------------------------------------------- knn K1: MFMA prefix -> conservative per-query threshold
// per-lane sorted top-8 (med3 chain, depth 1) + LDS merge popping the
// exact 16th smallest of the union of the query's 4 lane-top-8s (32 vals).
__global__ __launch_bounds__(256) void knn_prefix_kernel(
    const float4* __restrict__ pts4, const ushort* __restrict__ ptsC64,
    float* __restrict__ thrb)
{
    __shared__ __align__(16) char lbuf[10240];   // 128 rows x 80B
    __shared__ float mrg[4][16][36];             // 9 KB merge (9-stride rows)

    const int t    = threadIdx.x;
    const int wv   = t >> 6;
    const int lane = t & 63;
    const int l15  = lane & 15, l4 = lane >> 4;
    const int b    = blockIdx.y;
    const int qbase = (blockIdx.x * 4 + wv) * 16;

    // query fragment (B operand) — identical construction to scan
    const float4 p = pts4[(size_t)b * NN + qbase + l15];
    const ushort qhx = f2bf(p.x), qhy = f2bf(p.y), qhz = f2bf(p.z);
    const ushort qlx = f2bf(p.x - bf2f(qhx));
    const ushort qly = f2bf(p.y - bf2f(qhy));
    const ushort qlz = f2bf(p.z - bf2f(qhz));
    const ushort qsh = f2bf(p.w), qsl = f2bf(p.w - bf2f(qsh));
    short8 qf;
    if (l4 == 0)
        qf = short8{ (short)qhx, (short)qhy, (short)qhz, (short)qhx,
                     (short)qhy, (short)qhz, (short)qlx, (short)qly };
    else if (l4 == 1)
        qf = short8{ (short)qlz, (short)qlx, (short)qly, (short)qlz,
                     (short)BFONE, (short)BFONE, (short)qsh, (short)qsl };
    else
        qf = short8{ 0, 0, 0, 0, 0, 0, 0, 0 };

    float l0 = 3.0e38f, l1 = 3.0e38f, l2 = 3.0e38f, l3 = 3.0e38f;
    float l4r = 3.0e38f, l5 = 3.0e38f, l6 = 3.0e38f, l7 = 3.0e38f;

    const uint4* __restrict__ gsrc0 = (const uint4*)(ptsC64 + ((size_t)b * NN) * 32);
    // chunk s = rows s*512 .. s*512+127 -> uint4 offset s*2048
    uint4 r0 = gsrc0[t], r1 = gsrc0[t + 256];

#pragma unroll 1
    for (int s = 0; s < 16; ++s) {
        __syncthreads();                          // lds free
        *(uint4*)(lbuf + (t >> 2) * 80 + (t & 3) * 16) = r0;
        *(uint4*)(lbuf + ((t + 256) >> 2) * 80 + (t & 3) * 16) = r1;
        if (s < 15) {
            r0 = gsrc0[(s + 1) * 2048 + t];
            r1 = gsrc0[(s + 1) * 2048 + t + 256];
        }
        __syncthreads();                          // lds ready

#pragma unroll
        for (int i = 0; i < 8; ++i) {
            short8 cf = *(const short8*)(lbuf + (i * 16 + l15) * 80 + l4 * 16);
            f32x4 D = { 0.f, 0.f, 0.f, 0.f };
            D = __builtin_amdgcn_mfma_f32_16x16x32_bf16(cf, qf, D, 0, 0, 0);
#pragma unroll
            for (int reg = 0; reg < 4; ++reg) {
                float k = D[reg];
                float n0 = fminf(l0, k);
                float n1 = MED3(l0, l1, k);
                float n2 = MED3(l1, l2, k);
                float n3 = MED3(l2, l3, k);
                float n4 = MED3(l3, l4r, k);
                float n5 = MED3(l4r, l5, k);
                float n6 = MED3(l5, l6, k);
                float n7 = MED3(l6, l7, k);
                l0 = n0; l1 = n1; l2 = n2; l3 = n3;
                l4r = n4; l5 = n5; l6 = n6; l7 = n7;
            }
        }
    }

    // write sorted top-8 to merge buffer (9-stride rows, <=2-way banks)
    {
        float lv[8] = { l0, l1, l2, l3, l4r, l5, l6, l7 };
#pragma unroll
        for (int d = 0; d < 8; ++d) mrg[wv][l15][l4 * 9 + d] = lv[d];
    }
    __syncthreads();

    if (l4 == 0) {
        float h[4]; int kc[4];
#pragma unroll
        for (int s = 0; s < 4; ++s) { h[s] = mrg[wv][l15][s * 9]; kc[s] = 1; }
        float best = 3.0e38f;
        for (int o = 0; o < KK; ++o) {
            best = h[0]; int bs = 0;
#pragma unroll
            for (int s = 1; s < 4; ++s) { if (h[s] < best) { best = h[s]; bs = s; } }
#pragma unroll
            for (int s = 0; s < 4; ++s) {
                if (s == bs) {
                    h[s] = (kc[s] < 8) ? mrg[wv][l15][s * 9 + kc[s]] : 3.0e38f;
                    kc[s]++;
                }
            }
        }
        thrb[(size_t)b * NN + qbase + l15] = best;   // 16th of 32-union >= sample d16
    }
}

// ---------------------------------------------------------------- knn K2: MFMA full scan vs threshold
__global__ __launch_bounds__(256) void knn_scan_kernel(
    const float4* __restrict__ pts4, const ushort* __restrict__ ptsC64,
    const float* __restrict__ thrb, unsigned* __restrict__ bufm)
{
    __shared__ __align__(16) char lbuf[10240];   // 128 rows x 80B

    const int t    = threadIdx.x;
    const int wv   = t >> 6;
    const int lane = t & 63;
    const int l15  = lane & 15, l4 = lane >> 4;
    const int b    = blockIdx.y;
    const int z    = blockIdx.z;                 // candidate chunk (1024)
    const int qt   = blockIdx.x * 4 + wv;        // q-tile 0..511
    const int qbase = qt * 16;

    const float4 p = pts4[(size_t)b * NN + qbase + l15];
    const ushort qhx = f2bf(p.x), qhy = f2bf(p.y), qhz = f2bf(p.z);
    const ushort qlx = f2bf(p.x - bf2f(qhx));
    const ushort qly = f2bf(p.y - bf2f(qhy));
    const ushort qlz = f2bf(p.z - bf2f(qhz));
    const ushort qsh = f2bf(p.w), qsl = f2bf(p.w - bf2f(qsh));
    short8 qf;
    if (l4 == 0)
        qf = short8{ (short)qhx, (short)qhy, (short)qhz, (short)qhx,
                     (short)qhy, (short)qhz, (short)qlx, (short)qly };
    else if (l4 == 1)
        qf = short8{ (short)qlz, (short)qlx, (short)qly, (short)qlz,
                     (short)BFONE, (short)BFONE, (short)qsh, (short)qsl };
    else
        qf = short8{ 0, 0, 0, 0, 0, 0, 0, 0 };

    const float thrq = thrb[(size_t)b * NN + qbase + l15] * 1.001f + EPSF;

    const uint4* __restrict__ gsrc =
        (const uint4*)(ptsC64 + ((size_t)b * NN + (size_t)z * 1024) * 32);

    unsigned* __restrict__ op =
        bufm + (size_t)(b * NN + qbase + l15) * 256 + z * 32 + l4 * 8;

    uint4 r0 = gsrc[t], r1 = gsrc[t + 256];
    unsigned w4[4];

#pragma unroll 1
    for (int g = 0; g < 8; ++g) {
        __syncthreads();                          // lds free
        *(uint4*)(lbuf + (t >> 2) * 80 + (t & 3) * 16) = r0;
        *(uint4*)(lbuf + ((t + 256) >> 2) * 80 + (t & 3) * 16) = r1;
        if (g < 7) {
            r0 = gsrc[(g + 1) * 512 + t];
            r1 = gsrc[(g + 1) * 512 + t + 256];
        }
        __syncthreads();                          // lds ready

        unsigned acc = 0;
#pragma unroll
        for (int i = 0; i < 8; ++i) {
            short8 cf = *(const short8*)(lbuf + (i * 16 + l15) * 80 + l4 * 16);
            f32x4 D = { 0.f, 0.f, 0.f, 0.f };
            D = __builtin_amdgcn_mfma_f32_16x16x32_bf16(cf, qf, D, 0, 0, 0);
            acc = acc * 2u + (unsigned)(D[0] <= thrq);
            acc = acc * 2u + (unsigned)(D[1] <= thrq);
            acc = acc * 2u + (unsigned)(D[2] <= thrq);
            acc = acc * 2u + (unsigned)(D[3] <= thrq);
        }
        w4[g & 3] = acc;
        if ((g & 3) == 3)
            *(uint4*)(op + (g >> 2) * 4) = make_uint4(w4[0], w4[1], w4[2], w4[3]);
    }
}

// ---------------------------------------------------------------- knn K3: exact select (8 thr/query, padded sm3)
__global__ __launch_bounds__(256) void knn_select_kernel(
    const float4* __restrict__ pts4, const float4* __restrict__ pts4n,
    const unsigned* __restrict__ bufm,
    int* __restrict__ iout)
{
    __shared__ ull sm3[4][8][8][KK + 1];    // 34.8 KB (17-pad: k-loop walks banks)
    __shared__ ushort stash[STASH][256];    // 16 KB, transposed (conflict-free)

    const int t = threadIdx.x;
    const int wv = t >> 6, lane = t & 63;
    const int qq = lane & 7, hh = lane >> 3;
    const int q  = (blockIdx.x * 4 + wv) * 8 + qq;     // global query 0..16383
    const int b  = q >> 13;

    const float4 qp = pts4[q];
    ull list[KK];
#pragma unroll
    for (int i = 0; i < KK; ++i) list[i] = KINF;

    // ---- Phase A: decode mask words -> per-thread id stash
    const unsigned* __restrict__ mrow = bufm + (size_t)q * 256 + hh * 32;
    int pend = 0;
#pragma unroll 1
    for (int g4 = 0; g4 < 8; ++g4) {
        uint4 v = ((const uint4*)mrow)[g4];
        unsigned wsv[4] = { v.x, v.y, v.z, v.w };
#pragma unroll
        for (int j = 0; j < 4; ++j) {
            unsigned w = wsv[j];
            const int W = hh * 32 + g4 * 4 + j;
            const int cb = ((W >> 5) << 10) + ((W & 7) << 7) + (((W >> 3) & 3) << 2);
            while (w) {
                int p = __builtin_ctz(w);
                w &= w - 1;
                int m = 31 - p;
                int id = cb + ((m >> 2) << 4) + (m & 3);
                if (pend < STASH) {
                    stash[pend][t] = (ushort)id;
                    ++pend;
                } else {
                    float d = distq(qp, pts4n[b * NN + id]);
                    unsigned ud = __float_as_uint(d);
                    ud ^= ((unsigned)((int)ud >> 31)) | 0x80000000u;
                    ull k = ((ull)ud << 32) | (unsigned)id;
#pragma unroll
                    for (int i2 = KK - 1; i2 > 0; --i2) {
                        bool c1 = k < list[i2];
                        bool c2 = k < list[i2 - 1];
                        ull nd = c2 ? list[i2 - 1] : k;
                        list[i2] = c1 ? nd : list[i2];
                    }
                    list[0] = (k < list[0]) ? k : list[0];
                }
            }
        }
    }

    // ---- Phase B: uniform branchless insert loop (wave-max pend iters, 2-wide)
    for (int j = 0; ; j += 2) {
        if (!__any(j < pend)) break;
        int j1 = j + 1;
        int id0 = stash[(j  < pend) ? j  : 0][t];
        int id1 = stash[(j1 < pend) ? j1 : 0][t];
        float4 cn0 = pts4n[b * NN + id0];
        float4 cn1 = pts4n[b * NN + id1];

        float d0 = distq(qp, cn0);
        unsigned ud0 = __float_as_uint(d0);
        ud0 ^= ((unsigned)((int)ud0 >> 31)) | 0x80000000u;
        ull k0 = (j < pend) ? ((((ull)ud0) << 32) | (unsigned)id0) : KINF;
#pragma unroll
        for (int i2 = KK - 1; i2 > 0; --i2) {
            bool c1 = k0 < list[i2];
            bool c2 = k0 < list[i2 - 1];
            ull nd = c2 ? list[i2 - 1] : k0;
            list[i2] = c1 ? nd : list[i2];
        }
        list[0] = (k0 < list[0]) ? k0 : list[0];

        float d1 = distq(qp, cn1);
        unsigned ud1 = __float_as_uint(d1);
        ud1 ^= ((unsigned)((int)ud1 >> 31)) | 0x80000000u;
        ull k1 = (j1 < pend) ? ((((ull)ud1) << 32) | (unsigned)id1) : KINF;
#pragma unroll
        for (int i2 = KK - 1; i2 > 0; --i2) {
            bool c1 = k1 < list[i2];
            bool c2 = k1 < list[i2 - 1];
            ull nd = c2 ? list[i2 - 1] : k1;
            list[i2] = c1 ? nd : list[i2];
        }
        list[0] = (k1 < list[0]) ? k1 : list[0];
    }

#pragma unroll
    for (int k = 0; k < KK; ++k) sm3[wv][hh][qq][k] = list[k];

    if (hh == 0) {
        ull h[8]; int kc[8];
#pragma unroll
        for (int s = 0; s < 8; ++s) { h[s] = sm3[wv][s][qq][0]; kc[s] = 0; }
        int* op = iout + (size_t)q * KK;
        for (int o = 0; o < KK; ++o) {
            ull best = h[0]; int bs = 0;
#pragma unroll
            for (int s = 1; s < 8; ++s) { if (h[s] < best) { best = h[s]; bs = s; } }
            op[o] = (int)(unsigned)(best & 0xFFFFFFFFULL);
#pragma unroll
            for (int s = 0; s < 8; ++s) {
                if (s == bs) {
                    kc[s]++;
                    h[s] = (kc[s] < KK) ? sm3[wv][s][qq][kc[s]] : KINF;
                }
            }
        }
    }
}

// ---------------------------------------------------------------- attention (512 thr / 8 waves share W2; W1 in regs; 16 waves/CU) + cov
__global__ __launch_bounds__(512, 4) void attn_cov_kernel(
    const ushort* __restrict__ f1, const int* __restrict__ idx,
    const ushort* __restrict__ awb1, const float* __restrict__ ab1,
    const ushort* __restrict__ awb2, const float* __restrict__ ab2,
    ushort* __restrict__ fagg,
    const float4* __restrict__ pts4,
    const float* __restrict__ cw, const float* __restrict__ cb,
    ushort* __restrict__ fcov)
{
    __shared__ __align__(16) ushort w2l[64][136];      // 17.0 KB
    __shared__ __align__(16) ushort fkb[8][16][72];    // 18.0 KB
    __shared__ __align__(16) ushort hb[8][16][136];    // 34.0 KB  (total 69 KB -> 2 blocks/CU = 16 waves)

    const int t = threadIdx.x;

    if (blockIdx.x >= 256) {
        // ------------------------------ cov + mlp2 (blocks 256..287, 512 thr)
        int P = (blockIdx.x - 256) * 512 + t;
        int b = P >> 13;
        const int4* ip4 = (const int4*)(idx + (size_t)P * KK);
        int ids[KK];
#pragma unroll
        for (int g = 0; g < 4; ++g) {
            int4 v = ip4[g];
            ids[g * 4 + 0] = v.x; ids[g * 4 + 1] = v.y;
            ids[g * 4 + 2] = v.z; ids[g * 4 + 3] = v.w;
        }
        float px[KK], py[KK], pz[KK];
#pragma unroll
        for (int k = 0; k < KK; ++k) {
            float4 c = pts4[b * NN + ids[k]];
            px[k] = c.x; py[k] = c.y; pz[k] = c.z;
        }
        float mx = 0.f, my = 0.f, mz = 0.f;
#pragma unroll
        for (int k = 0; k < KK; ++k) { mx += px[k]; my += py[k]; mz += pz[k]; }
        mx *= (1.f / 16.f); my *= (1.f / 16.f); mz *= (1.f / 16.f);
        float c00 = 0, c01 = 0, c02 = 0, c11 = 0, c12 = 0, c22 = 0;
#pragma unroll
        for (int k = 0; k < KK; ++k) {
            float dx = px[k] - mx, dy = py[k] - my, dz = pz[k] - mz;
            c00 = fmaf(dx, dx, c00); c01 = fmaf(dx, dy, c01); c02 = fmaf(dx, dz, c02);
            c11 = fmaf(dy, dy, c11); c12 = fmaf(dy, dz, c12); c22 = fmaf(dz, dz, c22);
        }
        const float inv = 1.f / 16.f;
        float cf[9] = { c00 * inv, c01 * inv, c02 * inv,
                        c01 * inv, c11 * inv, c12 * inv,
                        c02 * inv, c12 * inv, c22 * inv };
        ushort* outp = fcov + (size_t)P * 32;
#pragma unroll
        for (int o = 0; o < 32; ++o) {
            float v = cb[o];
#pragma unroll
            for (int m = 0; m < 9; ++m) v = fmaf(cw[o * 9 + m], cf[m], v);
            outp[o] = f2bf(fmaxf(v, 0.f));
        }
        return;
    }

    // ------------------------------ attention (blocks 0..255, 8 waves x 8 points)
    const int wv = t >> 6, lane = t & 63;
    const int l15 = lane & 15, qd = lane >> 4;

    // W1 fragments in registers: rows tile*16+l15, cols qd*8 / 32+qd*8
    short8 w1f[8][2];
#pragma unroll
    for (int tile = 0; tile < 8; ++tile) {
        const ushort* pw = awb1 + (size_t)(tile * 16 + l15) * 64 + qd * 8;
        w1f[tile][0] = *(const short8*)(pw);
        w1f[tile][1] = *(const short8*)(pw + 32);
    }

    // W2 staged in LDS (vectorized bf16, pre-converted), shared by 8 waves
    for (int i = t * 8; i < 64 * 128; i += 512 * 8) {
        int r = i >> 7, c = i & 127;
        *(short8*)&w2l[r][c] = *(const short8*)(awb2 + i);
    }
    __syncthreads();

    const int W = blockIdx.x * 8 + wv;     // 0..2047
    for (int g = 0; g < 8; ++g) {
        const int P = W * 8 + g;
        const int b = P >> 13;

        float fc = bf2f(f1[(size_t)P * 64 + lane]);
        ushort fn[15];
#pragma unroll
        for (int j = 0; j < 15; ++j) {
            int nb = idx[(size_t)P * KK + 1 + j];
            fn[j] = f1[((size_t)b * NN + nb) * 64 + lane];
        }
#pragma unroll
        for (int j = 0; j < 15; ++j) fkb[wv][j][lane] = f2bf(bf2f(fn[j]) - fc);
        fkb[wv][15][lane] = 0;

        short8 a0 = *(const short8*)&fkb[wv][l15][qd * 8];
        short8 a1 = *(const short8*)&fkb[wv][l15][32 + qd * 8];

#pragma unroll
        for (int tile = 0; tile < 8; ++tile) {
            float bv = ab1[tile * 16 + l15];
            f32x4 acc = { bv, bv, bv, bv };
            acc = __builtin_amdgcn_mfma_f32_16x16x32_bf16(a0, w1f[tile][0], acc, 0, 0, 0);
            acc = __builtin_amdgcn_mfma_f32_16x16x32_bf16(a1, w1f[tile][1], acc, 0, 0, 0);
#pragma unroll
            for (int reg = 0; reg < 4; ++reg)
                hb[wv][qd * 4 + reg][tile * 16 + l15] = f2bf(fmaxf(acc[reg], 0.f));
        }

        short8 a2[4];
#pragma unroll
        for (int ks = 0; ks < 4; ++ks)
            a2[ks] = *(const short8*)&hb[wv][l15][ks * 32 + qd * 8];

        f32x4 L[4];
#pragma unroll
        for (int tile = 0; tile < 4; ++tile) {
            float bv = ab2[tile * 16 + l15];
            f32x4 acc = { bv, bv, bv, bv };
#pragma unroll
            for (int ks = 0; ks < 4; ++ks) {
                short8 bf = *(const short8*)&w2l[tile * 16 + l15][ks * 32 + qd * 8];
                acc = __builtin_amdgcn_mfma_f32_16x16x32_bf16(a2[ks], bf, acc, 0, 0, 0);
            }
            L[tile] = acc;
        }

        float fa[4];
#pragma unroll
        for (int tile = 0; tile < 4; ++tile) {
            float m1 = -3.0e38f;
#pragma unroll
            for (int reg = 0; reg < 4; ++reg)
                if (qd * 4 + reg < 15) m1 = fmaxf(m1, L[tile][reg]);
            m1 = fmaxf(m1, __shfl_xor(m1, 16));
            m1 = fmaxf(m1, __shfl_xor(m1, 32));
            float e[4], ssum = 0.f;
#pragma unroll
            for (int reg = 0; reg < 4; ++reg) {
                bool valid = (qd * 4 + reg < 15);
                e[reg] = valid ? __expf(L[tile][reg] - m1) : 0.f;
                ssum += e[reg];
            }
            ssum += __shfl_xor(ssum, 16);
            ssum += __shfl_xor(ssum, 32);
            float part = 0.f;
#pragma unroll
            for (int reg = 0; reg < 4; ++reg) {
                float fkv = bf2f(fkb[wv][qd * 4 + reg][tile * 16 + l15]);
                part = fmaf(e[reg], fkv, part);
            }
            part += __shfl_xor(part, 16);
            part += __shfl_xor(part, 32);
            fa[tile] = part / ssum;
        }
        if (qd == 0) {
#pragma unroll
            for (int tile = 0; tile < 4; ++tile)
                fagg[(size_t)P * 64 + tile * 16 + l15] = f2bf(fa[tile]);
        }
    }
}

// ---------------------------------------------------------------- mlp3 + output (bf16 MFMA, pre-converted weights)
__global__ __launch_bounds__(256) void mlp3_kernel(
    const ushort* __restrict__ fagg, const ushort* __restrict__ fcov,
    const ushort* __restrict__ w1b, const float* __restrict__ b1,
    const ushort* __restrict__ w2b, const float* __restrict__ b2,
    const float* __restrict__ x, float* __restrict__ out)
{
    __shared__ __align__(16) ushort fb[4][16][104];    // 13.3 KB
    __shared__ __align__(16) ushort hb[4][16][136];    // 17.4 KB

    const int t = threadIdx.x;
    const int wv = t >> 6, lane = t & 63;
    const int l15 = lane & 15, qd = lane >> 4;

    short8 w1f[8][3];
#pragma unroll
    for (int tile = 0; tile < 8; ++tile)
#pragma unroll
        for (int ks = 0; ks < 3; ++ks)
            w1f[tile][ks] = *(const short8*)(w1b + ((size_t)(tile * 16 + l15) * 96 + ks * 32 + qd * 8));
    short8 w2f[4];
#pragma unroll
    for (int ks = 0; ks < 4; ++ks) {
        short8 f = {};
        if (l15 < 12)
            f = *(const short8*)(w2b + ((size_t)l15 * 128 + ks * 32 + qd * 8));
        w2f[ks] = f;
    }

    const int T = blockIdx.x * 4 + wv;    // tile 0..1023

    {
        const int pt = lane >> 2, c4 = lane & 3;
        const ushort* fap = fagg + ((size_t)(T * 16 + pt) * 64 + c4 * 16);
        *(short8*)&fb[wv][pt][c4 * 16]     = *(const short8*)(fap);
        *(short8*)&fb[wv][pt][c4 * 16 + 8] = *(const short8*)(fap + 8);
        const ushort* fcp = fcov + ((size_t)(T * 16 + pt) * 32 + c4 * 8);
        *(short8*)&fb[wv][pt][64 + c4 * 8] = *(const short8*)(fcp);
    }

    short8 a[3];
#pragma unroll
    for (int ks = 0; ks < 3; ++ks)
        a[ks] = *(const short8*)&fb[wv][l15][ks * 32 + qd * 8];

#pragma unroll
    for (int tile = 0; tile < 8; ++tile) {
        float bv = b1[tile * 16 + l15];
        f32x4 acc = { bv, bv, bv, bv };
#pragma unroll
        for (int ks = 0; ks < 3; ++ks)
            acc = __builtin_amdgcn_mfma_f32_16x16x32_bf16(a[ks], w1f[tile][ks], acc, 0, 0, 0);
#pragma unroll
        for (int reg = 0; reg < 4; ++reg)
            hb[wv][qd * 4 + reg][tile * 16 + l15] = f2bf(fmaxf(acc[reg], 0.f));
    }

    short8 a2[4];
#pragma unroll
    for (int ks = 0; ks < 4; ++ks)
        a2[ks] = *(const short8*)&hb[wv][l15][ks * 32 + qd * 8];

    float bv2 = (l15 < 12) ? b2[l15] : 0.f;
    f32x4 acc = { bv2, bv2, bv2, bv2 };
#pragma unroll
    for (int ks = 0; ks < 4; ++ks)
        acc = __builtin_amdgcn_mfma_f32_16x16x32_bf16(a2[ks], w2f[ks], acc, 0, 0, 0);

    if (l15 < 12) {
        const int c = l15 >> 2, rr = l15 & 3;
#pragma unroll
        for (int reg = 0; reg < 4; ++reg) {
            int P = T * 16 + qd * 4 + reg;
            int b = P >> 13, n = P & (NN - 1);
            float xv = x[((size_t)b * 3 + c) * NN + n];
            out[(((size_t)b * 3 + c) * 4 + rr) * NN + n] = xv + 0.15f * acc[reg];
        }
    }
}

// ---------------------------------------------------------------- launch
extern "C" void kernel_launch(void* const* d_in, const int* in_sizes, int n_in,
                              void* d_out, int out_size, void* d_ws, size_t ws_size,
                              hipStream_t stream)
{
    (void)in_sizes; (void)n_in; (void)out_size; (void)ws_size;
    const float* x    = (const float*)d_in[0];
    const float* m1w1 = (const float*)d_in[1];
    const float* m1b1 = (const float*)d_in[2];
    const float* m1w2 = (const float*)d_in[3];
    const float* m1b2 = (const float*)d_in[4];
    const float* m2w1 = (const float*)d_in[5];
    const float* m2b1 = (const float*)d_in[6];
    const float* m3w1 = (const float*)d_in[7];
    const float* m3b1 = (const float*)d_in[8];
    const float* m3w2 = (const float*)d_in[9];
    const float* m3b2 = (const float*)d_in[10];
    const float* aw1  = (const float*)d_in[11];
    const float* ab1  = (const float*)d_in[12];
    const float* aw2  = (const float*)d_in[13];
    const float* ab2  = (const float*)d_in[14];
    float* out = (float*)d_out;

    char* ws = (char*)d_ws;
    float4* pts4   = (float4*)(ws + 0);           //   262144 B
    float4* pts4n  = (float4*)(ws + 262144);      //   262144 B
    float*  thrb   = (float*)(ws + 524288);       //    65536 B
    int*    idxb   = (int*)  (ws + 589824);       //  1048576 B
    ushort* ptsC64 = (ushort*)(ws + 1638400);     //  1048576 B (MFMA cand rows, 64B/pt)
    unsigned* bufm = (unsigned*)(ws + 2686976);   // 16777216 B (256 u32 mask words / query)
    ushort* f1b    = (ushort*)(ws + 19464192);    //  2097152 B
    ushort* fagg   = (ushort*)(ws + 21561344);    //  2097152 B
    ushort* fcov   = (ushort*)(ws + 23658496);    //  1048576 B
    ushort* awb1   = (ushort*)(ws + 24707072);    //    16384 B (bf16 att w1)
    ushort* awb2   = (ushort*)(ws + 24723456);    //    16384 B (bf16 att w2)
    ushort* m3w1b  = (ushort*)(ws + 24739840);    //    24576 B (bf16 mlp3 w1)
    ushort* m3w2b  = (ushort*)(ws + 24764416);    //     3072 B (bf16 mlp3 w2, end 24.8 MB)

    prep_f1_kernel<<<200, 256, 0, stream>>>(x, pts4, pts4n, ptsC64, m1w1, m1b1, m1w2, m1b2, f1b,
                                            aw1, aw2, m3w1, m3w2, awb1, awb2, m3w1b, m3w2b);
    knn_prefix_kernel<<<dim3(128, BB), 256, 0, stream>>>(pts4, ptsC64, thrb);
    knn_scan_kernel<<<dim3(128, BB, 8), 256, 0, stream>>>(pts4, ptsC64, thrb, bufm);
    knn_select_kernel<<<512, 256, 0, stream>>>(pts4, pts4n, bufm, idxb);
    attn_cov_kernel<<<288, 512, 0, stream>>>(f1b, idxb, awb1, ab1, awb2, ab2, fagg,
                                             pts4, m2w1, m2b1, fcov);
    mlp3_kernel<<<256, 256, 0, stream>>>(fagg, fcov, m3w1b, m3b1, m3w2b, m3b2, x, out);
}

// Round 14
// 214.125 us; speedup vs baseline: 1.0866x; 1.0866x over previous
//
#include <hip/hip_runtime.h>

#define BB 2
#define NN 8192
#define KK 16
#define QPB 64
#define STASH 32         // per-thread survivor id stash (LDS); overflow -> inline insert
#define EPSF 0.02f       // bf16-hi/lo MFMA distance error slack (bound ~3e-3, >3x margin)
typedef unsigned long long ull;
typedef unsigned short ushort;
#define KINF 0xFFFFFFFFFFFFFFFFULL
#define BFONE 0x3F80

typedef __attribute__((ext_vector_type(8))) short short8;
typedef __attribute__((ext_vector_type(4))) float f32x4;

#if __has_builtin(__builtin_amdgcn_fmed3f)
#define MED3(a,b,c) __builtin_amdgcn_fmed3f((a),(b),(c))
#else
#define MED3(a,b,c) fmaxf(fminf((a),(b)), fminf(fmaxf((a),(b)),(c)))
#endif

static __device__ __forceinline__ ushort f2bf(float f) {
    unsigned u = __float_as_uint(f);
    unsigned r = (u + 0x7FFFu + ((u >> 16) & 1u)) >> 16;
    return (ushort)r;
}
static __device__ __forceinline__ float bf2f(ushort s) {
    return __uint_as_float(((unsigned)s) << 16);
}

// exact distance form used by select (consistent => thr conservative):
// d = fma(qx,cnx, fma(qy,cny, fma(qz,cnz, qw+cnw))), cn = (-2x,-2y,-2z,sq)
static __device__ __forceinline__ float distq(const float4& qp, const float4& cn) {
    return fmaf(qp.x, cn.x, fmaf(qp.y, cn.y, fmaf(qp.z, cn.z, __fadd_rn(qp.w, cn.w))));
}

// ---------------------------------------------------------------- prep + f1 + weight pre-conversion
// blocks 0..63: pts4/pts4n/ptsC64 | 64..191: f1 (128 pts/block, 2 thr/pt)
// 192..199: weight bf16 pre-conversion
__global__ __launch_bounds__(256) void prep_f1_kernel(
    const float* __restrict__ x, float4* __restrict__ pts4, float4* __restrict__ pts4n,
    ushort* __restrict__ ptsC64,
    const float* __restrict__ w1, const float* __restrict__ b1,
    const float* __restrict__ w2, const float* __restrict__ b2,
    ushort* __restrict__ f1,
    const float* __restrict__ aw1, const float* __restrict__ aw2,
    const float* __restrict__ m3w1, const float* __restrict__ m3w2,
    ushort* __restrict__ awb1, ushort* __restrict__ awb2,
    ushort* __restrict__ m3w1b, ushort* __restrict__ m3w2b)
{
    if (blockIdx.x >= 192) {
        // ------------------------------ weight bf16 pre-conversion (blocks 192..199)
        int wt = (blockIdx.x - 192) * 256 + threadIdx.x;   // 0..2047
        for (int c = wt; c < 7552; c += 2048) {
            int i = c * 4;
            const float* s; ushort* d; int off;
            if (i < 8192)       { s = aw1;  d = awb1;  off = i; }
            else if (i < 16384) { s = aw2;  d = awb2;  off = i - 8192; }
            else if (i < 28672) { s = m3w1; d = m3w1b; off = i - 16384; }
            else                { s = m3w2; d = m3w2b; off = i - 28672; }
            float4 v = *(const float4*)(s + off);
            ushort4 o = { f2bf(v.x), f2bf(v.y), f2bf(v.z), f2bf(v.w) };
            *(ushort4*)(d + off) = o;
        }
        return;
    }
    if (blockIdx.x < 64) {
        int t = blockIdx.x * 256 + threadIdx.x;
        int b = t >> 13, n = t & (NN - 1);
        float x0 = x[(b * 3 + 0) * NN + n];
        float x1 = x[(b * 3 + 1) * NN + n];
        float x2 = x[(b * 3 + 2) * NN + n];
        float sq = fmaf(x2, x2, fmaf(x1, x1, __fmul_rn(x0, x0)));
        pts4[t]  = make_float4(x0, x1, x2, sq);
        pts4n[t] = make_float4(-2.f * x0, -2.f * x1, -2.f * x2, sq);

        // MFMA candidate row: K=16 bf16 (hi/lo split), padded to 32 (64B)
        float m2x = -2.f * x0, m2y = -2.f * x1, m2z = -2.f * x2;
        ushort hx = f2bf(m2x), hy = f2bf(m2y), hz = f2bf(m2z);
        ushort lx = f2bf(m2x - bf2f(hx));
        ushort ly = f2bf(m2y - bf2f(hy));
        ushort lz = f2bf(m2z - bf2f(hz));
        ushort sh = f2bf(sq), sl = f2bf(sq - bf2f(sh));
        short8 r0 = { (short)hx, (short)hy, (short)hz, (short)lx,
                      (short)ly, (short)lz, (short)hx, (short)hy };
        short8 r1 = { (short)hz, (short)lx, (short)ly, (short)lz,
                      (short)sh, (short)sl, (short)BFONE, (short)BFONE };
        short8 zz = { 0, 0, 0, 0, 0, 0, 0, 0 };
        ushort* cp = ptsC64 + (size_t)t * 32;
        *(short8*)(cp)      = r0;
        *(short8*)(cp + 8)  = r1;
        *(short8*)(cp + 16) = zz;
        *(short8*)(cp + 24) = zz;
    } else {
        // f1: 128 blocks x 128 points, 2 threads/point (t&1 = output half)
        int P = (blockIdx.x - 64) * 128 + (threadIdx.x >> 1);
        int half = threadIdx.x & 1;
        int b = P >> 13, n = P & (NN - 1);
        float x0 = x[(b * 3 + 0) * NN + n];
        float x1 = x[(b * 3 + 1) * NN + n];
        float x2 = x[(b * 3 + 2) * NN + n];
        float h[32];
#pragma unroll
        for (int o = 0; o < 32; ++o) {
            float v = fmaf(w1[o * 3 + 2], x2, fmaf(w1[o * 3 + 1], x1, fmaf(w1[o * 3 + 0], x0, b1[o])));
            h[o] = fmaxf(v, 0.f);
        }
#pragma unroll
        for (int i = 0; i < 8; ++i) {
            int o4 = half * 8 + i;
            float vv[4];
#pragma unroll
            for (int u = 0; u < 4; ++u) {
                int o = o4 * 4 + u;
                float v = b2[o];
#pragma unroll
                for (int k = 0; k < 32; ++k) v = fmaf(w2[o * 32 + k], h[k], v);
                vv[u] = fmaxf(v, 0.f);
            }
            ushort4 s = { f2bf(vv[0]), f2bf(vv[1]), f2bf(vv[2]), f2bf(vv[3]) };
            *(ushort4*)(f1 + (size_t)P * 64 + o4 * 4) = s;
        }
    }
}

// ---------------------------------------------------------------- knn K1: MFMA prefix -> conservative per-query threshold
// per-lane sorted top-8 (med3 chain, depth 1) + LDS merge popping the
// exact 16th smallest of the union of the query's 4 lane-top-8s (32 vals).
__global__ __launch_bounds__(256) void knn_prefix_kernel(
    const float4* __restrict__ pts4, const ushort* __restrict__ ptsC64,
    float* __restrict__ thrb)
{
    __shared__ __align__(16) char lbuf[10240];   // 128 rows x 80B
    __shared__ float mrg[4][16][36];             // 9 KB merge (9-stride rows)

    const int t    = threadIdx.x;
    const int wv   = t >> 6;
    const int lane = t & 63;
    const int l15  = lane & 15, l4 = lane >> 4;
    const int b    = blockIdx.y;
    const int qbase = (blockIdx.x * 4 + wv) * 16;

    // query fragment (B operand) — identical construction to scan
    const float4 p = pts4[(size_t)b * NN + qbase + l15];
    const ushort qhx = f2bf(p.x), qhy = f2bf(p.y), qhz = f2bf(p.z);
    const ushort qlx = f2bf(p.x - bf2f(qhx));
    const ushort qly = f2bf(p.y - bf2f(qhy));
    const ushort qlz = f2bf(p.z - bf2f(qhz));
    const ushort qsh = f2bf(p.w), qsl = f2bf(p.w - bf2f(qsh));
    short8 qf;
    if (l4 == 0)
        qf = short8{ (short)qhx, (short)qhy, (short)qhz, (short)qhx,
                     (short)qhy, (short)qhz, (short)qlx, (short)qly };
    else if (l4 == 1)
        qf = short8{ (short)qlz, (short)qlx, (short)qly, (short)qlz,
                     (short)BFONE, (short)BFONE, (short)qsh, (short)qsl };
    else
        qf = short8{ 0, 0, 0, 0, 0, 0, 0, 0 };

    float l0 = 3.0e38f, l1 = 3.0e38f, l2 = 3.0e38f, l3 = 3.0e38f;
    float l4r = 3.0e38f, l5 = 3.0e38f, l6 = 3.0e38f, l7 = 3.0e38f;

    const uint4* __restrict__ gsrc0 = (const uint4*)(ptsC64 + ((size_t)b * NN) * 32);
    // chunk s = rows s*512 .. s*512+127 -> uint4 offset s*2048
    uint4 r0 = gsrc0[t], r1 = gsrc0[t + 256];

#pragma unroll 1
    for (int s = 0; s < 16; ++s) {
        __syncthreads();                          // lds free
        *(uint4*)(lbuf + (t >> 2) * 80 + (t & 3) * 16) = r0;
        *(uint4*)(lbuf + ((t + 256) >> 2) * 80 + (t & 3) * 16) = r1;
        if (s < 15) {
            r0 = gsrc0[(s + 1) * 2048 + t];
            r1 = gsrc0[(s + 1) * 2048 + t + 256];
        }
        __syncthreads();                          // lds ready

#pragma unroll
        for (int i = 0; i < 8; ++i) {
            short8 cf = *(const short8*)(lbuf + (i * 16 + l15) * 80 + l4 * 16);
            f32x4 D = { 0.f, 0.f, 0.f, 0.f };
            D = __builtin_amdgcn_mfma_f32_16x16x32_bf16(cf, qf, D, 0, 0, 0);
#pragma unroll
            for (int reg = 0; reg < 4; ++reg) {
                float k = D[reg];
                float n0 = fminf(l0, k);
                float n1 = MED3(l0, l1, k);
                float n2 = MED3(l1, l2, k);
                float n3 = MED3(l2, l3, k);
                float n4 = MED3(l3, l4r, k);
                float n5 = MED3(l4r, l5, k);
                float n6 = MED3(l5, l6, k);
                float n7 = MED3(l6, l7, k);
                l0 = n0; l1 = n1; l2 = n2; l3 = n3;
                l4r = n4; l5 = n5; l6 = n6; l7 = n7;
            }
        }
    }

    // write sorted top-8 to merge buffer (9-stride rows, <=2-way banks)
    {
        float lv[8] = { l0, l1, l2, l3, l4r, l5, l6, l7 };
#pragma unroll
        for (int d = 0; d < 8; ++d) mrg[wv][l15][l4 * 9 + d] = lv[d];
    }
    __syncthreads();

    if (l4 == 0) {
        float h[4]; int kc[4];
#pragma unroll
        for (int s = 0; s < 4; ++s) { h[s] = mrg[wv][l15][s * 9]; kc[s] = 1; }
        float best = 3.0e38f;
        for (int o = 0; o < KK; ++o) {
            best = h[0]; int bs = 0;
#pragma unroll
            for (int s = 1; s < 4; ++s) { if (h[s] < best) { best = h[s]; bs = s; } }
#pragma unroll
            for (int s = 0; s < 4; ++s) {
                if (s == bs) {
                    h[s] = (kc[s] < 8) ? mrg[wv][l15][s * 9 + kc[s]] : 3.0e38f;
                    kc[s]++;
                }
            }
        }
        thrb[(size_t)b * NN + qbase + l15] = best;   // 16th of 32-union >= sample d16
    }
}

// ---------------------------------------------------------------- knn K2: MFMA full scan vs threshold
__global__ __launch_bounds__(256) void knn_scan_kernel(
    const float4* __restrict__ pts4, const ushort* __restrict__ ptsC64,
    const float* __restrict__ thrb, unsigned* __restrict__ bufm)
{
    __shared__ __align__(16) char lbuf[10240];   // 128 rows x 80B

    const int t    = threadIdx.x;
    const int wv   = t >> 6;
    const int lane = t & 63;
    const int l15  = lane & 15, l4 = lane >> 4;
    const int b    = blockIdx.y;
    const int z    = blockIdx.z;                 // candidate chunk (1024)
    const int qt   = blockIdx.x * 4 + wv;        // q-tile 0..511
    const int qbase = qt * 16;

    const float4 p = pts4[(size_t)b * NN + qbase + l15];
    const ushort qhx = f2bf(p.x), qhy = f2bf(p.y), qhz = f2bf(p.z);
    const ushort qlx = f2bf(p.x - bf2f(qhx));
    const ushort qly = f2bf(p.y - bf2f(qhy));
    const ushort qlz = f2bf(p.z - bf2f(qhz));
    const ushort qsh = f2bf(p.w), qsl = f2bf(p.w - bf2f(qsh));
    short8 qf;
    if (l4 == 0)
        qf = short8{ (short)qhx, (short)qhy, (short)qhz, (short)qhx,
                     (short)qhy, (short)qhz, (short)qlx, (short)qly };
    else if (l4 == 1)
        qf = short8{ (short)qlz, (short)qlx, (short)qly, (short)qlz,
                     (short)BFONE, (short)BFONE, (short)qsh, (short)qsl };
    else
        qf = short8{ 0, 0, 0, 0, 0, 0, 0, 0 };

    const float thrq = thrb[(size_t)b * NN + qbase + l15] * 1.001f + EPSF;

    const uint4* __restrict__ gsrc =
        (const uint4*)(ptsC64 + ((size_t)b * NN + (size_t)z * 1024) * 32);

    unsigned* __restrict__ op =
        bufm + (size_t)(b * NN + qbase + l15) * 256 + z * 32 + l4 * 8;

    uint4 r0 = gsrc[t], r1 = gsrc[t + 256];
    unsigned w4[4];

#pragma unroll 1
    for (int g = 0; g < 8; ++g) {
        __syncthreads();                          // lds free
        *(uint4*)(lbuf + (t >> 2) * 80 + (t & 3) * 16) = r0;
        *(uint4*)(lbuf + ((t + 256) >> 2) * 80 + (t & 3) * 16) = r1;
        if (g < 7) {
            r0 = gsrc[(g + 1) * 512 + t];
            r1 = gsrc[(g + 1) * 512 + t + 256];
        }
        __syncthreads();                          // lds ready

        unsigned acc = 0;
#pragma unroll
        for (int i = 0; i < 8; ++i) {
            short8 cf = *(const short8*)(lbuf + (i * 16 + l15) * 80 + l4 * 16);
            f32x4 D = { 0.f, 0.f, 0.f, 0.f };
            D = __builtin_amdgcn_mfma_f32_16x16x32_bf16(cf, qf, D, 0, 0, 0);
            acc = acc * 2u + (unsigned)(D[0] <= thrq);
            acc = acc * 2u + (unsigned)(D[1] <= thrq);
            acc = acc * 2u + (unsigned)(D[2] <= thrq);
            acc = acc * 2u + (unsigned)(D[3] <= thrq);
        }
        w4[g & 3] = acc;
        if ((g & 3) == 3)
            *(uint4*)(op + (g >> 2) * 4) = make_uint4(w4[0], w4[1], w4[2], w4[3]);
    }
}

// ---------------------------------------------------------------- knn K3: exact select (8 thr/query, padded sm3)
__global__ __launch_bounds__(256) void knn_select_kernel(
    const float4* __restrict__ pts4, const float4* __restrict__ pts4n,
    const unsigned* __restrict__ bufm,
    int* __restrict__ iout)
{
    __shared__ ull sm3[4][8][8][KK + 1];    // 34.8 KB (17-pad: k-loop walks banks)
    __shared__ ushort stash[STASH][256];    // 16 KB, transposed (conflict-free)

    const int t = threadIdx.x;
    const int wv = t >> 6, lane = t & 63;
    const int qq = lane & 7, hh = lane >> 3;
    const int q  = (blockIdx.x * 4 + wv) * 8 + qq;     // global query 0..16383
    const int b  = q >> 13;

    const float4 qp = pts4[q];
    ull list[KK];
#pragma unroll
    for (int i = 0; i < KK; ++i) list[i] = KINF;

    // ---- Phase A: decode mask words -> per-thread id stash
    const unsigned* __restrict__ mrow = bufm + (size_t)q * 256 + hh * 32;
    int pend = 0;
#pragma unroll 1
    for (int g4 = 0; g4 < 8; ++g4) {
        uint4 v = ((const uint4*)mrow)[g4];
        unsigned wsv[4] = { v.x, v.y, v.z, v.w };
#pragma unroll
        for (int j = 0; j < 4; ++j) {
            unsigned w = wsv[j];
            const int W = hh * 32 + g4 * 4 + j;
            const int cb = ((W >> 5) << 10) + ((W & 7) << 7) + (((W >> 3) & 3) << 2);
            while (w) {
                int p = __builtin_ctz(w);
                w &= w - 1;
                int m = 31 - p;
                int id = cb + ((m >> 2) << 4) + (m & 3);
                if (pend < STASH) {
                    stash[pend][t] = (ushort)id;
                    ++pend;
                } else {
                    float d = distq(qp, pts4n[b * NN + id]);
                    unsigned ud = __float_as_uint(d);
                    ud ^= ((unsigned)((int)ud >> 31)) | 0x80000000u;
                    ull k = ((ull)ud << 32) | (unsigned)id;
#pragma unroll
                    for (int i2 = KK - 1; i2 > 0; --i2) {
                        bool c1 = k < list[i2];
                        bool c2 = k < list[i2 - 1];
                        ull nd = c2 ? list[i2 - 1] : k;
                        list[i2] = c1 ? nd : list[i2];
                    }
                    list[0] = (k < list[0]) ? k : list[0];
                }
            }
        }
    }

    // ---- Phase B: uniform branchless insert loop (wave-max pend iters, 2-wide)
    for (int j = 0; ; j += 2) {
        if (!__any(j < pend)) break;
        int j1 = j + 1;
        int id0 = stash[(j  < pend) ? j  : 0][t];
        int id1 = stash[(j1 < pend) ? j1 : 0][t];
        float4 cn0 = pts4n[b * NN + id0];
        float4 cn1 = pts4n[b * NN + id1];

        float d0 = distq(qp, cn0);
        unsigned ud0 = __float_as_uint(d0);
        ud0 ^= ((unsigned)((int)ud0 >> 31)) | 0x80000000u;
        ull k0 = (j < pend) ? ((((ull)ud0) << 32) | (unsigned)id0) : KINF;
#pragma unroll
        for (int i2 = KK - 1; i2 > 0; --i2) {
            bool c1 = k0 < list[i2];
            bool c2 = k0 < list[i2 - 1];
            ull nd = c2 ? list[i2 - 1] : k0;
            list[i2] = c1 ? nd : list[i2];
        }
        list[0] = (k0 < list[0]) ? k0 : list[0];

        float d1 = distq(qp, cn1);
        unsigned ud1 = __float_as_uint(d1);
        ud1 ^= ((unsigned)((int)ud1 >> 31)) | 0x80000000u;
        ull k1 = (j1 < pend) ? ((((ull)ud1) << 32) | (unsigned)id1) : KINF;
#pragma unroll
        for (int i2 = KK - 1; i2 > 0; --i2) {
            bool c1 = k1 < list[i2];
            bool c2 = k1 < list[i2 - 1];
            ull nd = c2 ? list[i2 - 1] : k1;
            list[i2] = c1 ? nd : list[i2];
        }
        list[0] = (k1 < list[0]) ? k1 : list[0];
    }

#pragma unroll
    for (int k = 0; k < KK; ++k) sm3[wv][hh][qq][k] = list[k];

    if (hh == 0) {
        ull h[8]; int kc[8];
#pragma unroll
        for (int s = 0; s < 8; ++s) { h[s] = sm3[wv][s][qq][0]; kc[s] = 0; }
        int* op = iout + (size_t)q * KK;
        for (int o = 0; o < KK; ++o) {
            ull best = h[0]; int bs = 0;
#pragma unroll
            for (int s = 1; s < 8; ++s) { if (h[s] < best) { best = h[s]; bs = s; } }
            op[o] = (int)(unsigned)(best & 0xFFFFFFFFULL);
#pragma unroll
            for (int s = 0; s < 8; ++s) {
                if (s == bs) {
                    kc[s]++;
                    h[s] = (kc[s] < KK) ? sm3[wv][s][qq][kc[s]] : KINF;
                }
            }
        }
    }
}

// ---------------------------------------------------------------- attention (round-10 config: W1 in regs, 3 blocks/CU, inline gathers) + cov
__global__ __launch_bounds__(256, 3) void attn_cov_kernel(
    const ushort* __restrict__ f1, const int* __restrict__ idx,
    const ushort* __restrict__ awb1, const float* __restrict__ ab1,
    const ushort* __restrict__ awb2, const float* __restrict__ ab2,
    ushort* __restrict__ fagg,
    const float4* __restrict__ pts4,
    const float* __restrict__ cw, const float* __restrict__ cb,
    ushort* __restrict__ fcov)
{
    __shared__ __align__(16) ushort w2l[64][136];      // 17.0 KB
    __shared__ __align__(16) ushort fkb[4][16][72];    //  9.0 KB
    __shared__ __align__(16) ushort hb[4][16][136];    // 17.0 KB  (total 43 KB -> 3 blocks/CU)

    const int t = threadIdx.x;

    if (blockIdx.x >= 512) {
        // ------------------------------ cov + mlp2 (blocks 512..575)
        int P = (blockIdx.x - 512) * 256 + t;
        int b = P >> 13;
        const int4* ip4 = (const int4*)(idx + (size_t)P * KK);
        int ids[KK];
#pragma unroll
        for (int g = 0; g < 4; ++g) {
            int4 v = ip4[g];
            ids[g * 4 + 0] = v.x; ids[g * 4 + 1] = v.y;
            ids[g * 4 + 2] = v.z; ids[g * 4 + 3] = v.w;
        }
        float px[KK], py[KK], pz[KK];
#pragma unroll
        for (int k = 0; k < KK; ++k) {
            float4 c = pts4[b * NN + ids[k]];
            px[k] = c.x; py[k] = c.y; pz[k] = c.z;
        }
        float mx = 0.f, my = 0.f, mz = 0.f;
#pragma unroll
        for (int k = 0; k < KK; ++k) { mx += px[k]; my += py[k]; mz += pz[k]; }
        mx *= (1.f / 16.f); my *= (1.f / 16.f); mz *= (1.f / 16.f);
        float c00 = 0, c01 = 0, c02 = 0, c11 = 0, c12 = 0, c22 = 0;
#pragma unroll
        for (int k = 0; k < KK; ++k) {
            float dx = px[k] - mx, dy = py[k] - my, dz = pz[k] - mz;
            c00 = fmaf(dx, dx, c00); c01 = fmaf(dx, dy, c01); c02 = fmaf(dx, dz, c02);
            c11 = fmaf(dy, dy, c11); c12 = fmaf(dy, dz, c12); c22 = fmaf(dz, dz, c22);
        }
        const float inv = 1.f / 16.f;
        float cf[9] = { c00 * inv, c01 * inv, c02 * inv,
                        c01 * inv, c11 * inv, c12 * inv,
                        c02 * inv, c12 * inv, c22 * inv };
        ushort* outp = fcov + (size_t)P * 32;
#pragma unroll
        for (int o = 0; o < 32; ++o) {
            float v = cb[o];
#pragma unroll
            for (int m = 0; m < 9; ++m) v = fmaf(cw[o * 9 + m], cf[m], v);
            outp[o] = f2bf(fmaxf(v, 0.f));
        }
        return;
    }

    // ------------------------------ attention (blocks 0..511)
    const int wv = t >> 6, lane = t & 63;
    const int l15 = lane & 15, qd = lane >> 4;

    // W1 fragments in registers: rows tile*16+l15, cols qd*8 / 32+qd*8
    short8 w1f[8][2];
#pragma unroll
    for (int tile = 0; tile < 8; ++tile) {
        const ushort* pw = awb1 + (size_t)(tile * 16 + l15) * 64 + qd * 8;
        w1f[tile][0] = *(const short8*)(pw);
        w1f[tile][1] = *(const short8*)(pw + 32);
    }

    // W2 staged in LDS (vectorized bf16, pre-converted)
#pragma unroll
    for (int i = t * 8; i < 64 * 128; i += 256 * 8) {
        int r = i >> 7, c = i & 127;
        *(short8*)&w2l[r][c] = *(const short8*)(awb2 + i);
    }
    __syncthreads();

    const int W = blockIdx.x * 4 + wv;
    for (int g = 0; g < 8; ++g) {
        const int P = W * 8 + g;
        const int b = P >> 13;

        float fc = bf2f(f1[(size_t)P * 64 + lane]);
        ushort fn[15];
#pragma unroll
        for (int j = 0; j < 15; ++j) {
            int nb = idx[(size_t)P * KK + 1 + j];
            fn[j] = f1[((size_t)b * NN + nb) * 64 + lane];
        }
#pragma unroll
        for (int j = 0; j < 15; ++j) fkb[wv][j][lane] = f2bf(bf2f(fn[j]) - fc);
        fkb[wv][15][lane] = 0;

        short8 a0 = *(const short8*)&fkb[wv][l15][qd * 8];
        short8 a1 = *(const short8*)&fkb[wv][l15][32 + qd * 8];

#pragma unroll
        for (int tile = 0; tile < 8; ++tile) {
            float bv = ab1[tile * 16 + l15];
            f32x4 acc = { bv, bv, bv, bv };
            acc = __builtin_amdgcn_mfma_f32_16x16x32_bf16(a0, w1f[tile][0], acc, 0, 0, 0);
            acc = __builtin_amdgcn_mfma_f32_16x16x32_bf16(a1, w1f[tile][1], acc, 0, 0, 0);
#pragma unroll
            for (int reg = 0; reg < 4; ++reg)
                hb[wv][qd * 4 + reg][tile * 16 + l15] = f2bf(fmaxf(acc[reg], 0.f));
        }

        short8 a2[4];
#pragma unroll
        for (int ks = 0; ks < 4; ++ks)
            a2[ks] = *(const short8*)&hb[wv][l15][ks * 32 + qd * 8];

        f32x4 L[4];
#pragma unroll
        for (int tile = 0; tile < 4; ++tile) {
            float bv = ab2[tile * 16 + l15];
            f32x4 acc = { bv, bv, bv, bv };
#pragma unroll
            for (int ks = 0; ks < 4; ++ks) {
                short8 bf = *(const short8*)&w2l[tile * 16 + l15][ks * 32 + qd * 8];
                acc = __builtin_amdgcn_mfma_f32_16x16x32_bf16(a2[ks], bf, acc, 0, 0, 0);
            }
            L[tile] = acc;
        }

        float fa[4];
#pragma unroll
        for (int tile = 0; tile < 4; ++tile) {
            float m1 = -3.0e38f;
#pragma unroll
            for (int reg = 0; reg < 4; ++reg)
                if (qd * 4 + reg < 15) m1 = fmaxf(m1, L[tile][reg]);
            m1 = fmaxf(m1, __shfl_xor(m1, 16));
            m1 = fmaxf(m1, __shfl_xor(m1, 32));
            float e[4], ssum = 0.f;
#pragma unroll
            for (int reg = 0; reg < 4; ++reg) {
                bool valid = (qd * 4 + reg < 15);
                e[reg] = valid ? __expf(L[tile][reg] - m1) : 0.f;
                ssum += e[reg];
            }
            ssum += __shfl_xor(ssum, 16);
            ssum += __shfl_xor(ssum, 32);
            float part = 0.f;
#pragma unroll
            for (int reg = 0; reg < 4; ++reg) {
                float fkv = bf2f(fkb[wv][qd * 4 + reg][tile * 16 + l15]);
                part = fmaf(e[reg], fkv, part);
            }
            part += __shfl_xor(part, 16);
            part += __shfl_xor(part, 32);
            fa[tile] = part / ssum;
        }
        if (qd == 0) {
#pragma unroll
            for (int tile = 0; tile < 4; ++tile)
                fagg[(size_t)P * 64 + tile * 16 + l15] = f2bf(fa[tile]);
        }
    }
}

// ---------------------------------------------------------------- mlp3 + output (bf16 MFMA, pre-converted weights)
__global__ __launch_bounds__(256) void mlp3_kernel(
    const ushort* __restrict__ fagg, const ushort* __restrict__ fcov,
    const ushort* __restrict__ w1b, const float* __restrict__ b1,
    const ushort* __restrict__ w2b, const float* __restrict__ b2,
    const float* __restrict__ x, float* __restrict__ out)
{
    __shared__ __align__(16) ushort fb[4][16][104];    // 13.3 KB
    __shared__ __align__(16) ushort hb[4][16][136];    // 17.4 KB

    const int t = threadIdx.x;
    const int wv = t >> 6, lane = t & 63;
    const int l15 = lane & 15, qd = lane >> 4;

    short8 w1f[8][3];
#pragma unroll
    for (int tile = 0; tile < 8; ++tile)
#pragma unroll
        for (int ks = 0; ks < 3; ++ks)
            w1f[tile][ks] = *(const short8*)(w1b + ((size_t)(tile * 16 + l15) * 96 + ks * 32 + qd * 8));
    short8 w2f[4];
#pragma unroll
    for (int ks = 0; ks < 4; ++ks) {
        short8 f = {};
        if (l15 < 12)
            f = *(const short8*)(w2b + ((size_t)l15 * 128 + ks * 32 + qd * 8));
        w2f[ks] = f;
    }

    const int T = blockIdx.x * 4 + wv;    // tile 0..1023

    {
        const int pt = lane >> 2, c4 = lane & 3;
        const ushort* fap = fagg + ((size_t)(T * 16 + pt) * 64 + c4 * 16);
        *(short8*)&fb[wv][pt][c4 * 16]     = *(const short8*)(fap);
        *(short8*)&fb[wv][pt][c4 * 16 + 8] = *(const short8*)(fap + 8);
        const ushort* fcp = fcov + ((size_t)(T * 16 + pt) * 32 + c4 * 8);
        *(short8*)&fb[wv][pt][64 + c4 * 8] = *(const short8*)(fcp);
    }

    short8 a[3];
#pragma unroll
    for (int ks = 0; ks < 3; ++ks)
        a[ks] = *(const short8*)&fb[wv][l15][ks * 32 + qd * 8];

#pragma unroll
    for (int tile = 0; tile < 8; ++tile) {
        float bv = b1[tile * 16 + l15];
        f32x4 acc = { bv, bv, bv, bv };
#pragma unroll
        for (int ks = 0; ks < 3; ++ks)
            acc = __builtin_amdgcn_mfma_f32_16x16x32_bf16(a[ks], w1f[tile][ks], acc, 0, 0, 0);
#pragma unroll
        for (int reg = 0; reg < 4; ++reg)
            hb[wv][qd * 4 + reg][tile * 16 + l15] = f2bf(fmaxf(acc[reg], 0.f));
    }

    short8 a2[4];
#pragma unroll
    for (int ks = 0; ks < 4; ++ks)
        a2[ks] = *(const short8*)&hb[wv][l15][ks * 32 + qd * 8];

    float bv2 = (l15 < 12) ? b2[l15] : 0.f;
    f32x4 acc = { bv2, bv2, bv2, bv2 };
#pragma unroll
    for (int ks = 0; ks < 4; ++ks)
        acc = __builtin_amdgcn_mfma_f32_16x16x32_bf16(a2[ks], w2f[ks], acc, 0, 0, 0);

    if (l15 < 12) {
        const int c = l15 >> 2, rr = l15 & 3;
#pragma unroll
        for (int reg = 0; reg < 4; ++reg) {
            int P = T * 16 + qd * 4 + reg;
            int b = P >> 13, n = P & (NN - 1);
            float xv = x[((size_t)b * 3 + c) * NN + n];
            out[(((size_t)b * 3 + c) * 4 + rr) * NN + n] = xv + 0.15f * acc[reg];
        }
    }
}

// ---------------------------------------------------------------- launch
extern "C" void kernel_launch(void* const* d_in, const int* in_sizes, int n_in,
                              void* d_out, int out_size, void* d_ws, size_t ws_size,
                              hipStream_t stream)
{
    (void)in_sizes; (void)n_in; (void)out_size; (void)ws_size;
    const float* x    = (const float*)d_in[0];
    const float* m1w1 = (const float*)d_in[1];
    const float* m1b1 = (const float*)d_in[2];
    const float* m1w2 = (const float*)d_in[3];
    const float* m1b2 = (const float*)d_in[4];
    const float* m2w1 = (const float*)d_in[5];
    const float* m2b1 = (const float*)d_in[6];
    const float* m3w1 = (const float*)d_in[7];
    const float* m3b1 = (const float*)d_in[8];
    const float* m3w2 = (const float*)d_in[9];
    const float* m3b2 = (const float*)d_in[10];
    const float* aw1  = (const float*)d_in[11];
    const float* ab1  = (const float*)d_in[12];
    const float* aw2  = (const float*)d_in[13];
    const float* ab2  = (const float*)d_in[14];
    float* out = (float*)d_out;

    char* ws = (char*)d_ws;
    float4* pts4   = (float4*)(ws + 0);           //   262144 B
    float4* pts4n  = (float4*)(ws + 262144);      //   262144 B
    float*  thrb   = (float*)(ws + 524288);       //    65536 B
    int*    idxb   = (int*)  (ws + 589824);       //  1048576 B
    ushort* ptsC64 = (ushort*)(ws + 1638400);     //  1048576 B (MFMA cand rows, 64B/pt)
    unsigned* bufm = (unsigned*)(ws + 2686976);   // 16777216 B (256 u32 mask words / query)
    ushort* f1b    = (ushort*)(ws + 19464192);    //  2097152 B
    ushort* fagg   = (ushort*)(ws + 21561344);    //  2097152 B
    ushort* fcov   = (ushort*)(ws + 23658496);    //  1048576 B
    ushort* awb1   = (ushort*)(ws + 24707072);    //    16384 B (bf16 att w1)
    ushort* awb2   = (ushort*)(ws + 24723456);    //    16384 B (bf16 att w2)
    ushort* m3w1b  = (ushort*)(ws + 24739840);    //    24576 B (bf16 mlp3 w1)
    ushort* m3w2b  = (ushort*)(ws + 24764416);    //     3072 B (bf16 mlp3 w2, end 24.8 MB)

    prep_f1_kernel<<<200, 256, 0, stream>>>(x, pts4, pts4n, ptsC64, m1w1, m1b1, m1w2, m1b2, f1b,
                                            aw1, aw2, m3w1, m3w2, awb1, awb2, m3w1b, m3w2b);
    knn_prefix_kernel<<<dim3(128, BB), 256, 0, stream>>>(pts4, ptsC64, thrb);
    knn_scan_kernel<<<dim3(128, BB, 8), 256, 0, stream>>>(pts4, ptsC64, thrb, bufm);
    knn_select_kernel<<<512, 256, 0, stream>>>(pts4, pts4n, bufm, idxb);
    attn_cov_kernel<<<576, 256, 0, stream>>>(f1b, idxb, awb1, ab1, awb2, ab2, fagg,
                                             pts4, m2w1, m2b1, fcov);
    mlp3_kernel<<<256, 256, 0, stream>>>(fagg, fcov, m3w1b, m3b1, m3w2b, m3b2, x, out);
}